// Round 1
// baseline (255.023 us; speedup 1.0000x reference)
//
#include <hip/hip_runtime.h>
#include <hip/hip_bf16.h>
#include <math.h>

// ComplexProjection: out[b,r,p] = | sum_s complex(xr,xi)[b,r,s] * w[r,s,p] |
// B=32768, R=16, S=128, P=128. Memory-bound (~769 MB); bf16 MFMA for compute.

typedef __attribute__((ext_vector_type(8))) __bf16 bf16x8;
typedef __attribute__((ext_vector_type(4))) float f32x4;

#define B_TOT 32768
#define R_TOT 16
#define S_TOT 128
#define P_TOT 128
#define BLOCKS_PER_R 128
#define ROWS_PER_BLOCK 256  // B_TOT / BLOCKS_PER_R
#define RS (R_TOT * S_TOT)  // 2048: x row stride (floats)
#define RP (R_TOT * P_TOT)  // 2048: out row stride (floats)

__global__ __launch_bounds__(256) void cproj_kernel(
    const float* __restrict__ x_real,
    const float* __restrict__ x_imag,
    const float* __restrict__ proj,
    float* __restrict__ out)
{
    // W[r] staged bf16, transposed [p][s], XOR-swizzled on 16B units:
    // elem(p, s) = p*128 + (((s>>3) ^ (p&7)) << 3) + (s&7)
    __shared__ __attribute__((aligned(16))) __bf16 wlds[S_TOT * P_TOT];

    const int tid = threadIdx.x;
    const int r   = blockIdx.x >> 7;
    const int br  = blockIdx.x & (BLOCKS_PER_R - 1);

    // ---- stage W[r] -> LDS (fp32 coalesced read, bf16 swizzled write) ----
    const float* wr = proj + (size_t)r * (S_TOT * P_TOT);
    for (int idx = tid; idx < S_TOT * P_TOT; idx += 256) {
        int s = idx >> 7;      // row of W (k index)
        int p = idx & 127;     // col of W
        float v = wr[idx];
        wlds[p * 128 + ((((s >> 3) ^ (p & 7)) << 3)) + (s & 7)] = (__bf16)v;
    }
    __syncthreads();

    const int lane = tid & 63;
    const int wid  = tid >> 6;   // 0..3 waves
    const int m    = lane & 15;  // A row / B col / D col index
    const int g    = lane >> 4;  // 0..3 k-group / D row group
    const int b_base = br * ROWS_PER_BLOCK;

    for (int it = 0; it < 4; ++it) {
        const int b0  = b_base + it * 64 + wid * 16;  // this wave's 16-row strip
        const int row = b0 + m;
        const float* pr = x_real + (size_t)row * RS + r * S_TOT;
        const float* pi = x_imag + (size_t)row * RS + r * S_TOT;

        // A fragments: lane holds A[row][kk*32 + g*8 .. +7], converted to bf16
        bf16x8 ar[4], ai[4];
        #pragma unroll
        for (int kk = 0; kk < 4; ++kk) {
            const int kb = kk * 32 + g * 8;
            f32x4 f0 = *(const f32x4*)(pr + kb);
            f32x4 f1 = *(const f32x4*)(pr + kb + 4);
            f32x4 h0 = *(const f32x4*)(pi + kb);
            f32x4 h1 = *(const f32x4*)(pi + kb + 4);
            bf16x8 a, b;
            #pragma unroll
            for (int j = 0; j < 4; ++j) {
                a[j]     = (__bf16)f0[j];
                a[j + 4] = (__bf16)f1[j];
                b[j]     = (__bf16)h0[j];
                b[j + 4] = (__bf16)h1[j];
            }
            ar[kk] = a;
            ai[kk] = b;
        }

        f32x4 accr[8], acci[8];
        #pragma unroll
        for (int n = 0; n < 8; ++n) {
            accr[n] = (f32x4)0.0f;
            acci[n] = (f32x4)0.0f;
        }

        #pragma unroll
        for (int kk = 0; kk < 4; ++kk) {
            const int sb = kk * 4 + g;  // 16B-unit index along s
            #pragma unroll
            for (int n = 0; n < 8; ++n) {
                const int p = n * 16 + m;
                const bf16x8 w =
                    *(const bf16x8*)&wlds[p * 128 + ((sb ^ (m & 7)) << 3)];
                // B frag shared between real and imag MFMAs
                accr[n] = __builtin_amdgcn_mfma_f32_16x16x32_bf16(ar[kk], w, accr[n], 0, 0, 0);
                acci[n] = __builtin_amdgcn_mfma_f32_16x16x32_bf16(ai[kk], w, acci[n], 0, 0, 0);
            }
        }

        // Epilogue: D lane mapping (verified m89): col = lane&15, row = (lane>>4)*4 + j
        float* po = out + (size_t)(b0 + g * 4) * RP + r * P_TOT + m;
        #pragma unroll
        for (int n = 0; n < 8; ++n) {
            #pragma unroll
            for (int j = 0; j < 4; ++j) {
                float re = accr[n][j];
                float im = acci[n][j];
                po[(size_t)j * RP + n * 16] = sqrtf(re * re + im * im);
            }
        }
    }
}

extern "C" void kernel_launch(void* const* d_in, const int* in_sizes, int n_in,
                              void* d_out, int out_size, void* d_ws, size_t ws_size,
                              hipStream_t stream) {
    const float* x_real = (const float*)d_in[0];
    const float* x_imag = (const float*)d_in[1];
    const float* proj   = (const float*)d_in[2];
    float* out = (float*)d_out;

    dim3 grid(R_TOT * BLOCKS_PER_R);  // 2048 blocks: 8/CU
    dim3 block(256);
    cproj_kernel<<<grid, block, 0, stream>>>(x_real, x_imag, proj, out);
}